// Round 2
// baseline (95.516 us; speedup 1.0000x reference)
//
#include <hip/hip_runtime.h>
#include <hip/hip_bf16.h>
#include <stdint.h>

// ---------------------------------------------------------------------------
// FMICL loss on MI355X — R11.
//   loss = -mean(s_pos) + 64 * ( sum_offdiag exp(-(2-2*G_ij)/2) / (N(N-1)) + 1e-8 )
//   G = Q @ Q^T, Q = fp4-e2m1(normalize(z1) * 32)  -- f8f6f4 MFMA, unit scales,
//   epilogue rescale g = acc / 1024. Gram symmetry makes any k-order / nibble
//   convention cancel between A and B.
//
// R11 changes vs R9 (88.4us) [R10's cooperative launch hung the container --
// reverted to regular launches; kept the two independent improvements]:
//  - gram staging double-buffered (BKB 128B -> 64B, 2 x 16KB LDS = 32KB, still
//    3 blocks/CU): round r+1's global_load_lds DMA flies under round r's MFMA;
//    ONE barrier per round instead of issue->drain->compute->barrier.
//  - finalize fused into gram via last-block device-scope atomic (threadfence
//    release -> atomicAdd -> threadfence acquire; counter zeroed by kernel 1,
//    ordered by the dispatch boundary). Removes the 3rd dispatch + boundary.
//
// ws layout: [0, 2MB) fp4 Q ; float spos[4096] ; float star[528] ; uint done
// ---------------------------------------------------------------------------

#define AS1 __attribute__((address_space(1)))
#define AS3 __attribute__((address_space(3)))

typedef unsigned short u16;
typedef uint8_t  u8;
typedef int    i32x4 __attribute__((ext_vector_type(4)));
typedef int    i32x8 __attribute__((ext_vector_type(8)));
typedef float  f32x4 __attribute__((ext_vector_type(4)));

constexpr int   D      = 1024;            // feature dim == GEMM K (elements)
constexpr int   DB     = D / 2;           // Q row stride in BYTES (fp4)
constexpr int   N      = 4096;            // rows per half
constexpr int   TM     = 128;             // tile M = tile N
constexpr int   BKB    = 64;              // K-step per round in BYTES (=128 elems)
constexpr int   ROUNDS = DB / BKB;        // 8
constexpr int   NB     = N / TM;          // 32 tiles per side
constexpr int   NTRI   = NB * (NB + 1) / 2;  // 528 triangle tiles
constexpr float EPS    = 1e-8f;
constexpr float ALPHA  = 64.0f;

__device__ __forceinline__ void async_load16(const void* g, void* l) {
    __builtin_amdgcn_global_load_lds((AS1 void*)g, (AS3 void*)l, 16, 0, 0);
}

// fp32 -> fp4 e2m1 nibble of round(|x|*32), sign bit 0x8.
__device__ __forceinline__ int fp4_of(float v) {
    const float y = fabsf(v) * 32.0f;
    int n = (y < 0.25f) ? 0 : (y < 0.75f) ? 1 : (y < 1.25f) ? 2 :
            (y < 1.75f) ? 3 : (y < 2.5f)  ? 4 : (y < 3.5f)  ? 5 :
            (y < 5.0f)  ? 6 : 7;
    return n | ((v < 0.0f) ? 8 : 0);
}

// ---------------------------------------------------------------------------
// Kernel 1: per row-pair i: normalize z1_i, z2_i (fp32), store fp4 Q row,
// compute s_pos_i -> spos[i]. Thread t packs elements [4t,4t+4) -> one u16.
// Block 0 thread 0 also zeroes the gram completion counter (visible to the
// gram dispatch via the launch boundary).
// ---------------------------------------------------------------------------
__global__ __launch_bounds__(256) void norm_spos_kernel(
    const float* __restrict__ z, u8* __restrict__ q, float* __restrict__ spos,
    unsigned int* __restrict__ done)
{
    const int row = blockIdx.x;   // 0..4095
    const int t   = threadIdx.x;  // 0..255
    const int lane = t & 63, wave = t >> 6;

    if (row == 0 && t == 0) *done = 0u;

    const float4 a = ((const float4*)(z + (size_t)row       * D))[t];
    const float4 b = ((const float4*)(z + (size_t)(row + N) * D))[t];

    float s1 = a.x*a.x + a.y*a.y + a.z*a.z + a.w*a.w;
    float s2 = b.x*b.x + b.y*b.y + b.z*b.z + b.w*b.w;
    #pragma unroll
    for (int off = 32; off; off >>= 1) {
        s1 += __shfl_down(s1, off);
        s2 += __shfl_down(s2, off);
    }
    __shared__ float r1[4], r2[4], r3[4];
    if (lane == 0) { r1[wave] = s1; r2[wave] = s2; }
    __syncthreads();
    const float ss1 = r1[0] + r1[1] + r1[2] + r1[3];
    const float ss2 = r2[0] + r2[1] + r2[2] + r2[3];
    const float inv1 = 1.0f / fmaxf(sqrtf(ss1), 1e-12f);
    const float inv2 = 1.0f / fmaxf(sqrtf(ss2), 1e-12f);

    float4 an, bn;
    an.x = a.x * inv1; an.y = a.y * inv1; an.z = a.z * inv1; an.w = a.w * inv1;
    bn.x = b.x * inv2; bn.y = b.y * inv2; bn.z = b.z * inv2; bn.w = b.w * inv2;

    const int pk = fp4_of(an.x) | (fp4_of(an.y) << 4) |
                   (fp4_of(an.z) << 8) | (fp4_of(an.w) << 12);
    ((u16*)q)[row * (DB / 2) + t] = (u16)pk;

    const float dx = an.x - bn.x, dy = an.y - bn.y;
    const float dz = an.z - bn.z, dw = an.w - bn.w;
    float dp = dx*dx + dy*dy + dz*dz + dw*dw;
    #pragma unroll
    for (int off = 32; off; off >>= 1) dp += __shfl_down(dp, off);
    if (lane == 0) r3[wave] = dp;
    __syncthreads();
    if (t == 0) {
        const float d_pos = r3[0] + r3[1] + r3[2] + r3[3];
        const float g     = expf(-0.5f * d_pos);
        spos[row] = logf(g + EPS) + 1.0f;
    }
}

// ---------------------------------------------------------------------------
// Kernel 2: fused Gram + exp-sum over the (bi<=bj) triangle of 128x128 tiles,
// double-buffered staging, last-block scalar finalize.
// 256 threads = 4 waves, each wave a 64x64 sub-tile = 4x4 of 16x16x128 fp4
// MFMA (f8f6f4, cbsz=blgp=4, unit scales). 8 rounds of K=128 (64 B/row).
//
// LDS tiles [128 rows][64 B]: 16B granule g of row r stored at slot g^(r&3).
// global_load_lds dest stays linear in lane order; only the global SOURCE
// granule is permuted. Read of slot fq^(r&3) returns granule fq exactly.
// Fragment = ONE b128 per lane (16 B = 32 fp4 = K-slice).
// ---------------------------------------------------------------------------
__global__ __launch_bounds__(256, 3) void gram_kernel(
    const u8* __restrict__ Q, const float* __restrict__ spos,
    float* __restrict__ star_part, unsigned int* __restrict__ done,
    float* __restrict__ out)
{
    // [buf][A|B][128 rows * 64 B] = 32 KB double-buffered staging
    __shared__ __align__(16) u8 lds[2][2][TM * BKB];
    __shared__ float wsum[4];
    __shared__ int lastFlag;

    // triangle decode: blockIdx.x -> (bi, bj), bi <= bj
    int bi = 0, rem = blockIdx.x;
    while (rem >= NB - bi) { rem -= NB - bi; ++bi; }
    const int bj    = bi + rem;
    const int rowA0 = bi * TM, rowB0 = bj * TM;
    const bool diag = (bi == bj);

    const int t    = threadIdx.x;
    const int lane = t & 63;
    const int wave = t >> 6;
    const int wm   = (wave & 1) * 64;
    const int wn   = (wave >> 1) * 64;
    const int fr   = lane & 15;        // fragment row (m or n)
    const int fq   = lane >> 4;        // k-quad 0..3 (32 elements each)

    // staging: 512 16B-granules per operand per round; thread owns p = t+256j
    const u8* gAr[2]; const u8* gBr[2]; int dOff[2];
    #pragma unroll
    for (int j = 0; j < 2; ++j) {
        const int p = t + 256 * j;
        const int r = p >> 2;                // row 0..127 (4 granules/row)
        const int c = (p & 3) ^ (r & 3);     // XOR swizzle (self-inverse)
        gAr[j] = Q + (size_t)(rowA0 + r) * DB + c * 16;
        gBr[j] = Q + (size_t)(rowB0 + r) * DB + c * 16;
        dOff[j] = p * 16;
    }

    f32x4 acc[4][4];
    #pragma unroll
    for (int mt = 0; mt < 4; ++mt)
        #pragma unroll
        for (int nt = 0; nt < 4; ++nt)
            acc[mt][nt] = f32x4{0.f, 0.f, 0.f, 0.f};

    auto stage = [&](int rd, int buf) {
        const int o = rd * BKB;
        #pragma unroll
        for (int j = 0; j < 2; ++j) {
            async_load16(gAr[j] + o, &lds[buf][0][dOff[j]]);
            async_load16(gBr[j] + o, &lds[buf][1][dOff[j]]);
        }
    };

    auto compute = [&](int buf) {
        const u8* lA = &lds[buf][0][0];
        const u8* lB = &lds[buf][1][0];
        i32x8 bf[4];
        #pragma unroll
        for (int nt = 0; nt < 4; ++nt) {
            const int r = wn + nt * 16 + fr;
            const i32x4 v = *(const i32x4*)(lB + r * BKB + ((fq ^ (r & 3)) * 16));
            bf[nt][0] = v[0]; bf[nt][1] = v[1]; bf[nt][2] = v[2]; bf[nt][3] = v[3];
            bf[nt][4] = 0;    bf[nt][5] = 0;    bf[nt][6] = 0;    bf[nt][7] = 0;
        }
        #pragma unroll
        for (int mt = 0; mt < 4; ++mt) {
            const int r = wm + mt * 16 + fr;
            const i32x4 v = *(const i32x4*)(lA + r * BKB + ((fq ^ (r & 3)) * 16));
            i32x8 af;
            af[0] = v[0]; af[1] = v[1]; af[2] = v[2]; af[3] = v[3];
            af[4] = 0;    af[5] = 0;    af[6] = 0;    af[7] = 0;
            #pragma unroll
            for (int nt = 0; nt < 4; ++nt)
                acc[mt][nt] = __builtin_amdgcn_mfma_scale_f32_16x16x128_f8f6f4(
                    af, bf[nt], acc[mt][nt],
                    4, 4,               // cbsz=fp4, blgp=fp4
                    0, 0x7f7f7f7f,      // scale A: e8m0 127 = 1.0
                    0, 0x7f7f7f7f);     // scale B
        }
    };

    // 2-phase pipeline: stage(r+1) is in flight under compute(r); the single
    // end-of-round barrier (its vmcnt(0) drain) both completes that DMA and
    // protects the buffer swap.
    stage(0, 0);
    __syncthreads();
    for (int rd = 0; rd < ROUNDS; ++rd) {
        const int cur = rd & 1;
        if (rd + 1 < ROUNDS) stage(rd + 1, cur ^ 1);
        compute(cur);
        __syncthreads();
    }

    // Epilogue: g = acc/1024 (undo 32x per-operand encoding);
    // e = exp(-max(2-2g,0)/2); diag tile masks i==j; off-diag x2.
    constexpr float INV = 1.0f / 1024.0f;
    float lsum = 0.0f;
    #pragma unroll
    for (int mt = 0; mt < 4; ++mt) {
        #pragma unroll
        for (int nt = 0; nt < 4; ++nt) {
            #pragma unroll
            for (int r = 0; r < 4; ++r) {
                const float g  = acc[mt][nt][r] * INV;
                const int   gi = wm + mt * 16 + fq * 4 + r;   // local row
                const int   gj = wn + nt * 16 + fr;           // local col
                const float d2 = fmaxf(2.0f - 2.0f * g, 0.0f);
                const float e  = __expf(-0.5f * d2);
                lsum += (diag && gi == gj) ? 0.0f : e;
            }
        }
    }
    #pragma unroll
    for (int off = 32; off; off >>= 1) lsum += __shfl_down(lsum, off);
    if (lane == 0) wsum[wave] = lsum;
    __syncthreads();
    if (t == 0) {
        star_part[blockIdx.x] = (diag ? 1.0f : 2.0f) *
                                (wsum[0] + wsum[1] + wsum[2] + wsum[3]);
        __threadfence();                       // release star_part (device scope)
        const unsigned int prev = atomicAdd(done, 1u);
        lastFlag = (prev == (unsigned int)(NTRI - 1));
    }
    __syncthreads();

    // Last block to finish assembles the scalar loss (one boundary saved).
    if (lastFlag) {
        __threadfence();                       // acquire: invalidate stale cache
        float s1 = 0.0f, s2 = 0.0f;
        for (int i = t; i < N;    i += 256) s1 += spos[i];
        for (int i = t; i < NTRI; i += 256) s2 += star_part[i];
        #pragma unroll
        for (int off = 32; off; off >>= 1) {
            s1 += __shfl_down(s1, off);
            s2 += __shfl_down(s2, off);
        }
        __shared__ float f1[4], f2[4];
        if (lane == 0) { f1[wave] = s1; f2[wave] = s2; }
        __syncthreads();
        if (t == 0) {
            const float spos_sum  = f1[0] + f1[1] + f1[2] + f1[3];
            const float star_sum  = f2[0] + f2[1] + f2[2] + f2[3];
            const float star_mean = star_sum / ((float)N * (float)(N - 1)) + EPS;
            out[0] = -spos_sum / (float)N + ALPHA * star_mean;
        }
    }
}

// ---------------------------------------------------------------------------
extern "C" void kernel_launch(void* const* d_in, const int* in_sizes, int n_in,
                              void* d_out, int out_size, void* d_ws, size_t ws_size,
                              hipStream_t stream)
{
    (void)in_sizes; (void)n_in; (void)out_size; (void)ws_size;
    const float*  z    = (const float*)d_in[0];
    float*        out  = (float*)d_out;
    u8*           q    = (u8*)d_ws;                                  // 2 MB fp4
    float*        spos = (float*)((char*)d_ws + (size_t)N * DB);     // 4096 f
    float*        star = spos + N;                                   // 528 f
    unsigned int* done = (unsigned int*)(star + NTRI);               // 1 u32

    hipLaunchKernelGGL(norm_spos_kernel, dim3(N),    dim3(256), 0, stream,
                       z, q, spos, done);
    hipLaunchKernelGGL(gram_kernel,      dim3(NTRI), dim3(256), 0, stream,
                       q, spos, star, done, out);
}

// Round 3
// 95.272 us; speedup vs baseline: 1.0026x; 1.0026x over previous
//
#include <hip/hip_runtime.h>
#include <hip/hip_bf16.h>
#include <stdint.h>

// ---------------------------------------------------------------------------
// FMICL loss on MI355X — R12.
//   loss = -mean(s_pos) + 64 * ( sum_offdiag exp(-(2-2*G_ij)/2) / (N(N-1)) + 1e-8 )
//   G = Q @ Q^T, Q = fp4-e2m1(normalize(z1) * 32)  -- f8f6f4 MFMA, unit scales,
//   epilogue rescale g = acc / 1024. Gram symmetry makes any k-order / nibble
//   convention cancel between A and B.
//
// R12 = exact R9 gram structure (88.4us verified; R11's BKB=64 double-buffer
// regressed to 95.5us -- with 3 blocks/CU the DMA drain was already hidden by
// cross-block TLP, and halved rounds just added barrier overhead) + ONE
// isolated change: the 1-block finalize dispatch is fused into gram via a
// last-block device-scope atomic (threadfence release -> atomicAdd ->
// threadfence acquire; counter zeroed by kernel 1, ordered by the dispatch
// boundary). Tests the fusion alone vs the verified baseline.
//
// ws layout: [0, 2MB) fp4 Q ; float spos[4096] ; float star[528] ; uint done
// ---------------------------------------------------------------------------

#define AS1 __attribute__((address_space(1)))
#define AS3 __attribute__((address_space(3)))

typedef unsigned short u16;
typedef uint8_t  u8;
typedef int    i32x4 __attribute__((ext_vector_type(4)));
typedef int    i32x8 __attribute__((ext_vector_type(8)));
typedef float  f32x4 __attribute__((ext_vector_type(4)));

constexpr int   D     = 1024;         // feature dim == GEMM K (elements)
constexpr int   DB    = D / 2;        // Q row stride in BYTES (fp4)
constexpr int   N     = 4096;         // rows per half
constexpr int   TM    = 128;          // tile M = tile N
constexpr int   BKB   = 128;          // K-step per staging round in BYTES (=256 elems)
constexpr int   NB    = N / TM;       // 32 tiles per side
constexpr int   NTRI  = NB * (NB + 1) / 2;  // 528 triangle tiles
constexpr float EPS   = 1e-8f;
constexpr float ALPHA = 64.0f;

__device__ __forceinline__ void async_load16(const void* g, void* l) {
    __builtin_amdgcn_global_load_lds((AS1 void*)g, (AS3 void*)l, 16, 0, 0);
}

// fp32 -> fp4 e2m1 nibble of round(|x|*32), sign bit 0x8.
__device__ __forceinline__ int fp4_of(float v) {
    const float y = fabsf(v) * 32.0f;
    int n = (y < 0.25f) ? 0 : (y < 0.75f) ? 1 : (y < 1.25f) ? 2 :
            (y < 1.75f) ? 3 : (y < 2.5f)  ? 4 : (y < 3.5f)  ? 5 :
            (y < 5.0f)  ? 6 : 7;
    return n | ((v < 0.0f) ? 8 : 0);
}

// ---------------------------------------------------------------------------
// Kernel 1: per row-pair i: normalize z1_i, z2_i (fp32), store fp4 Q row,
// compute s_pos_i -> spos[i]. Thread t packs elements [4t,4t+4) -> one u16.
// Block 0 thread 0 also zeroes the gram completion counter (visible to the
// gram dispatch via the launch boundary).
// ---------------------------------------------------------------------------
__global__ __launch_bounds__(256) void norm_spos_kernel(
    const float* __restrict__ z, u8* __restrict__ q, float* __restrict__ spos,
    unsigned int* __restrict__ done)
{
    const int row = blockIdx.x;   // 0..4095
    const int t   = threadIdx.x;  // 0..255
    const int lane = t & 63, wave = t >> 6;

    if (row == 0 && t == 0) *done = 0u;

    const float4 a = ((const float4*)(z + (size_t)row       * D))[t];
    const float4 b = ((const float4*)(z + (size_t)(row + N) * D))[t];

    float s1 = a.x*a.x + a.y*a.y + a.z*a.z + a.w*a.w;
    float s2 = b.x*b.x + b.y*b.y + b.z*b.z + b.w*b.w;
    #pragma unroll
    for (int off = 32; off; off >>= 1) {
        s1 += __shfl_down(s1, off);
        s2 += __shfl_down(s2, off);
    }
    __shared__ float r1[4], r2[4], r3[4];
    if (lane == 0) { r1[wave] = s1; r2[wave] = s2; }
    __syncthreads();
    const float ss1 = r1[0] + r1[1] + r1[2] + r1[3];
    const float ss2 = r2[0] + r2[1] + r2[2] + r2[3];
    const float inv1 = 1.0f / fmaxf(sqrtf(ss1), 1e-12f);
    const float inv2 = 1.0f / fmaxf(sqrtf(ss2), 1e-12f);

    float4 an, bn;
    an.x = a.x * inv1; an.y = a.y * inv1; an.z = a.z * inv1; an.w = a.w * inv1;
    bn.x = b.x * inv2; bn.y = b.y * inv2; bn.z = b.z * inv2; bn.w = b.w * inv2;

    const int pk = fp4_of(an.x) | (fp4_of(an.y) << 4) |
                   (fp4_of(an.z) << 8) | (fp4_of(an.w) << 12);
    ((u16*)q)[row * (DB / 2) + t] = (u16)pk;

    const float dx = an.x - bn.x, dy = an.y - bn.y;
    const float dz = an.z - bn.z, dw = an.w - bn.w;
    float dp = dx*dx + dy*dy + dz*dz + dw*dw;
    #pragma unroll
    for (int off = 32; off; off >>= 1) dp += __shfl_down(dp, off);
    if (lane == 0) r3[wave] = dp;
    __syncthreads();
    if (t == 0) {
        const float d_pos = r3[0] + r3[1] + r3[2] + r3[3];
        const float g     = expf(-0.5f * d_pos);
        spos[row] = logf(g + EPS) + 1.0f;
    }
}

// ---------------------------------------------------------------------------
// Kernel 2: fused Gram + exp-sum over the (bi<=bj) triangle of 128x128 tiles.
// 256 threads = 4 waves, each wave a 64x64 sub-tile = 4x4 of 16x16x128 fp4
// MFMA (f8f6f4, cbsz=blgp=4, unit scales). 4 K-iters of 256 elements (128 B).
// Last block to finish assembles the scalar loss (saves the 3rd dispatch).
//
// LDS tiles [128 rows][128 B]: 16B granule g of row r stored at slot g^(r&7).
// global_load_lds dest stays linear in lane order; only the global SOURCE
// granule is permuted. Fragment = ONE b128 per lane (16 B = 32 fp4 = K-slice).
// ---------------------------------------------------------------------------
__global__ __launch_bounds__(256, 3) void gram_kernel(
    const u8* __restrict__ Q, const float* __restrict__ spos,
    float* __restrict__ star_part, unsigned int* __restrict__ done,
    float* __restrict__ out)
{
    __shared__ __align__(16) u8 lA[TM * BKB];  // 16 KB
    __shared__ __align__(16) u8 lB[TM * BKB];  // 16 KB
    __shared__ float wsum[4];
    __shared__ int lastFlag;

    // triangle decode: blockIdx.x -> (bi, bj), bi <= bj
    int bi = 0, rem = blockIdx.x;
    while (rem >= NB - bi) { rem -= NB - bi; ++bi; }
    const int bj    = bi + rem;
    const int rowA0 = bi * TM, rowB0 = bj * TM;
    const bool diag = (bi == bj);

    const int t    = threadIdx.x;
    const int lane = t & 63;
    const int wave = t >> 6;
    const int wm   = (wave & 1) * 64;
    const int wn   = (wave >> 1) * 64;
    const int fr   = lane & 15;        // fragment row (m or n)
    const int fq   = lane >> 4;        // k-quad 0..3 (32 elements each)

    // staging: 1024 16B-granules per tile, thread handles p = t + 256*j
    const u8* gA[4]; const u8* gB[4]; u8* dA[4]; u8* dB[4];
    #pragma unroll
    for (int j = 0; j < 4; ++j) {
        const int p = t + 256 * j;
        const int r = p >> 3;
        const int c = (p & 7) ^ (r & 7);   // XOR swizzle (self-inverse)
        gA[j] = Q + (size_t)(rowA0 + r) * DB + c * 16;
        gB[j] = Q + (size_t)(rowB0 + r) * DB + c * 16;
        dA[j] = &lA[p * 16];
        dB[j] = &lB[p * 16];
    }

    f32x4 acc[4][4];
    #pragma unroll
    for (int mt = 0; mt < 4; ++mt)
        #pragma unroll
        for (int nt = 0; nt < 4; ++nt)
            acc[mt][nt] = f32x4{0.f, 0.f, 0.f, 0.f};

    for (int k0 = 0; k0 < DB; k0 += BKB) {   // byte offset within Q row
        #pragma unroll
        for (int j = 0; j < 4; ++j) {
            async_load16(gA[j] + k0, dA[j]);
            async_load16(gB[j] + k0, dB[j]);
        }
        __syncthreads();   // drains vmcnt for the LDS-DMA

        #pragma unroll
        for (int kk = 0; kk < 2; ++kk) {     // two K=128 MFMA steps per stage
            // preload B fragments, then stream A one mt at a time
            i32x8 bf[4];
            #pragma unroll
            for (int nt = 0; nt < 4; ++nt) {
                const int r = wn + nt * 16 + fr;
                const i32x4 v = ((const i32x4*)&lB[r * BKB])[(kk * 4 + fq) ^ (r & 7)];
                bf[nt][0] = v[0]; bf[nt][1] = v[1]; bf[nt][2] = v[2]; bf[nt][3] = v[3];
                bf[nt][4] = 0;    bf[nt][5] = 0;    bf[nt][6] = 0;    bf[nt][7] = 0;
            }
            #pragma unroll
            for (int mt = 0; mt < 4; ++mt) {
                const int r = wm + mt * 16 + fr;
                const i32x4 v = ((const i32x4*)&lA[r * BKB])[(kk * 4 + fq) ^ (r & 7)];
                i32x8 af;
                af[0] = v[0]; af[1] = v[1]; af[2] = v[2]; af[3] = v[3];
                af[4] = 0;    af[5] = 0;    af[6] = 0;    af[7] = 0;
                #pragma unroll
                for (int nt = 0; nt < 4; ++nt)
                    acc[mt][nt] = __builtin_amdgcn_mfma_scale_f32_16x16x128_f8f6f4(
                        af, bf[nt], acc[mt][nt],
                        4, 4,               // cbsz=fp4, blgp=fp4
                        0, 0x7f7f7f7f,      // scale A: e8m0 127 = 1.0
                        0, 0x7f7f7f7f);     // scale B
            }
        }

        __syncthreads();   // protect LDS before next staging round
    }

    // Epilogue: g = acc/1024 (undo 32x per-operand encoding);
    // e = exp(-max(2-2g,0)/2); diag tile masks i==j; off-diag x2.
    constexpr float INV = 1.0f / 1024.0f;
    float lsum = 0.0f;
    #pragma unroll
    for (int mt = 0; mt < 4; ++mt) {
        #pragma unroll
        for (int nt = 0; nt < 4; ++nt) {
            #pragma unroll
            for (int r = 0; r < 4; ++r) {
                const float g  = acc[mt][nt][r] * INV;
                const int   gi = wm + mt * 16 + fq * 4 + r;   // local row
                const int   gj = wn + nt * 16 + fr;           // local col
                const float d2 = fmaxf(2.0f - 2.0f * g, 0.0f);
                const float e  = __expf(-0.5f * d2);
                lsum += (diag && gi == gj) ? 0.0f : e;
            }
        }
    }
    #pragma unroll
    for (int off = 32; off; off >>= 1) lsum += __shfl_down(lsum, off);
    if (lane == 0) wsum[wave] = lsum;
    __syncthreads();
    if (t == 0) {
        star_part[blockIdx.x] = (diag ? 1.0f : 2.0f) *
                                (wsum[0] + wsum[1] + wsum[2] + wsum[3]);
        __threadfence();                       // release star_part (device scope)
        const unsigned int prev = atomicAdd(done, 1u);
        lastFlag = (prev == (unsigned int)(NTRI - 1));
    }
    __syncthreads();

    // Last block to finish assembles the scalar loss (one boundary saved).
    if (lastFlag) {
        __threadfence();                       // acquire: order reads after atomic
        float s1 = 0.0f, s2 = 0.0f;
        for (int i = t; i < N;    i += 256) s1 += spos[i];
        for (int i = t; i < NTRI; i += 256) s2 += star_part[i];
        #pragma unroll
        for (int off = 32; off; off >>= 1) {
            s1 += __shfl_down(s1, off);
            s2 += __shfl_down(s2, off);
        }
        __shared__ float f1[4], f2[4];
        if (lane == 0) { f1[wave] = s1; f2[wave] = s2; }
        __syncthreads();
        if (t == 0) {
            const float spos_sum  = f1[0] + f1[1] + f1[2] + f1[3];
            const float star_sum  = f2[0] + f2[1] + f2[2] + f2[3];
            const float star_mean = star_sum / ((float)N * (float)(N - 1)) + EPS;
            out[0] = -spos_sum / (float)N + ALPHA * star_mean;
        }
    }
}

// ---------------------------------------------------------------------------
extern "C" void kernel_launch(void* const* d_in, const int* in_sizes, int n_in,
                              void* d_out, int out_size, void* d_ws, size_t ws_size,
                              hipStream_t stream)
{
    (void)in_sizes; (void)n_in; (void)out_size; (void)ws_size;
    const float*  z    = (const float*)d_in[0];
    float*        out  = (float*)d_out;
    u8*           q    = (u8*)d_ws;                                  // 2 MB fp4
    float*        spos = (float*)((char*)d_ws + (size_t)N * DB);     // 4096 f
    float*        star = spos + N;                                   // 528 f
    unsigned int* done = (unsigned int*)(star + NTRI);               // 1 u32

    hipLaunchKernelGGL(norm_spos_kernel, dim3(N),    dim3(256), 0, stream,
                       z, q, spos, done);
    hipLaunchKernelGGL(gram_kernel,      dim3(NTRI), dim3(256), 0, stream,
                       q, spos, star, done, out);
}

// Round 4
// 86.613 us; speedup vs baseline: 1.1028x; 1.1000x over previous
//
#include <hip/hip_runtime.h>
#include <hip/hip_bf16.h>
#include <stdint.h>

// ---------------------------------------------------------------------------
// FMICL loss on MI355X — R13.
//   loss = -mean(s_pos) + 64 * ( sum_offdiag exp(-(2-2*G_ij)/2) / (N(N-1)) + 1e-8 )
//   G = Q @ Q^T, Q = fp4-e2m1(normalize(z1) * 32)  -- f8f6f4 MFMA, unit scales,
//   epilogue rescale g = acc / 1024. Gram symmetry makes any k-order / nibble
//   convention cancel between A and B.
//
// Attribution so far: R11(fusion+dbuf)=95.5, R12(fusion only)=95.3, R9=88.4
//   => atomic finalize fusion costs ~7us (device-scope fences = per-XCD L2
//      writeback/invalidate in 528 blocks); double-buffer neutral. Both out.
//
// R13 = R9 3-dispatch structure + ONE isolated change: gram uses 512 threads
// (8 waves, 2x4 of 64x32 sub-tiles) instead of 256 (4 waves of 64x64).
// Why: 528 blocks ~ 2.06/CU means only ~2 waves/SIMD were active -- gram is
// latency-bound (MFMA floor ~2.5us, L2 fetch ~3us, observed ~20us). Same
// grid, LDS layout, swizzle, rounds; only wave->subtile mapping changes.
// launch_bounds(512,4): 2 blocks/CU, ~4 waves/SIMD, LDS 64KB/CU of 160.
//
// ws layout: [0, 2MB) fp4 Q ; float spos[4096] ; float star[528]
// ---------------------------------------------------------------------------

#define AS1 __attribute__((address_space(1)))
#define AS3 __attribute__((address_space(3)))

typedef unsigned short u16;
typedef uint8_t  u8;
typedef int    i32x4 __attribute__((ext_vector_type(4)));
typedef int    i32x8 __attribute__((ext_vector_type(8)));
typedef float  f32x4 __attribute__((ext_vector_type(4)));

constexpr int   D     = 1024;         // feature dim == GEMM K (elements)
constexpr int   DB    = D / 2;        // Q row stride in BYTES (fp4)
constexpr int   N     = 4096;         // rows per half
constexpr int   TM    = 128;          // tile M = tile N
constexpr int   BKB   = 128;          // K-step per staging round in BYTES (=256 elems)
constexpr int   NB    = N / TM;       // 32 tiles per side
constexpr int   NTRI  = NB * (NB + 1) / 2;  // 528 triangle tiles
constexpr float EPS   = 1e-8f;
constexpr float ALPHA = 64.0f;

__device__ __forceinline__ void async_load16(const void* g, void* l) {
    __builtin_amdgcn_global_load_lds((AS1 void*)g, (AS3 void*)l, 16, 0, 0);
}

// fp32 -> fp4 e2m1 nibble of round(|x|*32), sign bit 0x8.
__device__ __forceinline__ int fp4_of(float v) {
    const float y = fabsf(v) * 32.0f;
    int n = (y < 0.25f) ? 0 : (y < 0.75f) ? 1 : (y < 1.25f) ? 2 :
            (y < 1.75f) ? 3 : (y < 2.5f)  ? 4 : (y < 3.5f)  ? 5 :
            (y < 5.0f)  ? 6 : 7;
    return n | ((v < 0.0f) ? 8 : 0);
}

// ---------------------------------------------------------------------------
// Kernel 1: per row-pair i: normalize z1_i, z2_i (fp32), store fp4 Q row,
// compute s_pos_i -> spos[i]. Thread t packs elements [4t,4t+4) -> one u16.
// ---------------------------------------------------------------------------
__global__ __launch_bounds__(256) void norm_spos_kernel(
    const float* __restrict__ z, u8* __restrict__ q, float* __restrict__ spos)
{
    const int row = blockIdx.x;   // 0..4095
    const int t   = threadIdx.x;  // 0..255
    const int lane = t & 63, wave = t >> 6;

    const float4 a = ((const float4*)(z + (size_t)row       * D))[t];
    const float4 b = ((const float4*)(z + (size_t)(row + N) * D))[t];

    float s1 = a.x*a.x + a.y*a.y + a.z*a.z + a.w*a.w;
    float s2 = b.x*b.x + b.y*b.y + b.z*b.z + b.w*b.w;
    #pragma unroll
    for (int off = 32; off; off >>= 1) {
        s1 += __shfl_down(s1, off);
        s2 += __shfl_down(s2, off);
    }
    __shared__ float r1[4], r2[4], r3[4];
    if (lane == 0) { r1[wave] = s1; r2[wave] = s2; }
    __syncthreads();
    const float ss1 = r1[0] + r1[1] + r1[2] + r1[3];
    const float ss2 = r2[0] + r2[1] + r2[2] + r2[3];
    const float inv1 = 1.0f / fmaxf(sqrtf(ss1), 1e-12f);
    const float inv2 = 1.0f / fmaxf(sqrtf(ss2), 1e-12f);

    float4 an, bn;
    an.x = a.x * inv1; an.y = a.y * inv1; an.z = a.z * inv1; an.w = a.w * inv1;
    bn.x = b.x * inv2; bn.y = b.y * inv2; bn.z = b.z * inv2; bn.w = b.w * inv2;

    const int pk = fp4_of(an.x) | (fp4_of(an.y) << 4) |
                   (fp4_of(an.z) << 8) | (fp4_of(an.w) << 12);
    ((u16*)q)[row * (DB / 2) + t] = (u16)pk;

    const float dx = an.x - bn.x, dy = an.y - bn.y;
    const float dz = an.z - bn.z, dw = an.w - bn.w;
    float dp = dx*dx + dy*dy + dz*dz + dw*dw;
    #pragma unroll
    for (int off = 32; off; off >>= 1) dp += __shfl_down(dp, off);
    if (lane == 0) r3[wave] = dp;
    __syncthreads();
    if (t == 0) {
        const float d_pos = r3[0] + r3[1] + r3[2] + r3[3];
        const float g     = expf(-0.5f * d_pos);
        spos[row] = logf(g + EPS) + 1.0f;
    }
}

// ---------------------------------------------------------------------------
// Kernel 2: fused Gram + exp-sum over the (bi<=bj) triangle of 128x128 tiles.
// 512 threads = 8 waves in 2x4; each wave a 64x32 sub-tile = 4x2 of
// 16x16x128 fp4 MFMA (f8f6f4, cbsz=blgp=4, unit scales). 4 K-iters of 256
// elements (128 B).
//
// LDS tiles [128 rows][128 B]: 16B granule g of row r stored at slot g^(r&7).
// global_load_lds dest stays linear in lane order; only the global SOURCE
// granule is permuted. Fragment = ONE b128 per lane (16 B = 32 fp4 = K-slice).
// ---------------------------------------------------------------------------
__global__ __launch_bounds__(512, 4) void gram_kernel(
    const u8* __restrict__ Q, float* __restrict__ star_part)
{
    __shared__ __align__(16) u8 lA[TM * BKB];  // 16 KB
    __shared__ __align__(16) u8 lB[TM * BKB];  // 16 KB
    __shared__ float wsum[8];

    // triangle decode: blockIdx.x -> (bi, bj), bi <= bj
    int bi = 0, rem = blockIdx.x;
    while (rem >= NB - bi) { rem -= NB - bi; ++bi; }
    const int bj    = bi + rem;
    const int rowA0 = bi * TM, rowB0 = bj * TM;
    const bool diag = (bi == bj);

    const int t    = threadIdx.x;   // 0..511
    const int lane = t & 63;
    const int wave = t >> 6;        // 0..7
    const int wm   = (wave & 1) * 64;    // m-half
    const int wn   = (wave >> 1) * 32;   // n-quarter
    const int fr   = lane & 15;          // fragment row (m or n)
    const int fq   = lane >> 4;          // k-quad 0..3 (32 elements each)

    // staging: 1024 16B-granules per tile, thread handles p = t + 512*j
    const u8* gA[2]; const u8* gB[2]; u8* dA[2]; u8* dB[2];
    #pragma unroll
    for (int j = 0; j < 2; ++j) {
        const int p = t + 512 * j;
        const int r = p >> 3;
        const int c = (p & 7) ^ (r & 7);   // XOR swizzle (self-inverse)
        gA[j] = Q + (size_t)(rowA0 + r) * DB + c * 16;
        gB[j] = Q + (size_t)(rowB0 + r) * DB + c * 16;
        dA[j] = &lA[p * 16];
        dB[j] = &lB[p * 16];
    }

    f32x4 acc[4][2];
    #pragma unroll
    for (int mt = 0; mt < 4; ++mt)
        #pragma unroll
        for (int nt = 0; nt < 2; ++nt)
            acc[mt][nt] = f32x4{0.f, 0.f, 0.f, 0.f};

    for (int k0 = 0; k0 < DB; k0 += BKB) {   // byte offset within Q row
        #pragma unroll
        for (int j = 0; j < 2; ++j) {
            async_load16(gA[j] + k0, dA[j]);
            async_load16(gB[j] + k0, dB[j]);
        }
        __syncthreads();   // drains vmcnt for the LDS-DMA

        #pragma unroll
        for (int kk = 0; kk < 2; ++kk) {     // two K=128 MFMA steps per stage
            // preload B fragments, then stream A one mt at a time
            i32x8 bf[2];
            #pragma unroll
            for (int nt = 0; nt < 2; ++nt) {
                const int r = wn + nt * 16 + fr;
                const i32x4 v = ((const i32x4*)&lB[r * BKB])[(kk * 4 + fq) ^ (r & 7)];
                bf[nt][0] = v[0]; bf[nt][1] = v[1]; bf[nt][2] = v[2]; bf[nt][3] = v[3];
                bf[nt][4] = 0;    bf[nt][5] = 0;    bf[nt][6] = 0;    bf[nt][7] = 0;
            }
            #pragma unroll
            for (int mt = 0; mt < 4; ++mt) {
                const int r = wm + mt * 16 + fr;
                const i32x4 v = ((const i32x4*)&lA[r * BKB])[(kk * 4 + fq) ^ (r & 7)];
                i32x8 af;
                af[0] = v[0]; af[1] = v[1]; af[2] = v[2]; af[3] = v[3];
                af[4] = 0;    af[5] = 0;    af[6] = 0;    af[7] = 0;
                #pragma unroll
                for (int nt = 0; nt < 2; ++nt)
                    acc[mt][nt] = __builtin_amdgcn_mfma_scale_f32_16x16x128_f8f6f4(
                        af, bf[nt], acc[mt][nt],
                        4, 4,               // cbsz=fp4, blgp=fp4
                        0, 0x7f7f7f7f,      // scale A: e8m0 127 = 1.0
                        0, 0x7f7f7f7f);     // scale B
            }
        }

        __syncthreads();   // protect LDS before next staging round
    }

    // Epilogue: g = acc/1024 (undo 32x per-operand encoding);
    // e = exp(-max(2-2g,0)/2); diag tile masks i==j; off-diag x2.
    constexpr float INV = 1.0f / 1024.0f;
    float lsum = 0.0f;
    #pragma unroll
    for (int mt = 0; mt < 4; ++mt) {
        #pragma unroll
        for (int nt = 0; nt < 2; ++nt) {
            #pragma unroll
            for (int r = 0; r < 4; ++r) {
                const float g  = acc[mt][nt][r] * INV;
                const int   gi = wm + mt * 16 + fq * 4 + r;   // local row
                const int   gj = wn + nt * 16 + fr;           // local col
                const float d2 = fmaxf(2.0f - 2.0f * g, 0.0f);
                const float e  = __expf(-0.5f * d2);
                lsum += (diag && gi == gj) ? 0.0f : e;
            }
        }
    }
    #pragma unroll
    for (int off = 32; off; off >>= 1) lsum += __shfl_down(lsum, off);
    if (lane == 0) wsum[wave] = lsum;
    __syncthreads();
    if (t == 0) {
        float s = 0.0f;
        #pragma unroll
        for (int w = 0; w < 8; ++w) s += wsum[w];
        star_part[blockIdx.x] = (diag ? 1.0f : 2.0f) * s;
    }
}

// ---------------------------------------------------------------------------
// Kernel 3: sum the partials, assemble the scalar loss.
// ---------------------------------------------------------------------------
__global__ __launch_bounds__(256) void finalize_kernel(
    const float* __restrict__ spos, const float* __restrict__ star,
    float* __restrict__ out)
{
    const int t = threadIdx.x, lane = t & 63, wave = t >> 6;
    float s1 = 0.0f, s2 = 0.0f;
    for (int i = t; i < N;    i += 256) s1 += spos[i];
    for (int i = t; i < NTRI; i += 256) s2 += star[i];
    #pragma unroll
    for (int off = 32; off; off >>= 1) {
        s1 += __shfl_down(s1, off);
        s2 += __shfl_down(s2, off);
    }
    __shared__ float r1[4], r2[4];
    if (lane == 0) { r1[wave] = s1; r2[wave] = s2; }
    __syncthreads();
    if (t == 0) {
        const float spos_sum = r1[0] + r1[1] + r1[2] + r1[3];
        const float star_sum = r2[0] + r2[1] + r2[2] + r2[3];
        const float star_mean = star_sum / ((float)N * (float)(N - 1)) + EPS;
        out[0] = -spos_sum / (float)N + ALPHA * star_mean;
    }
}

// ---------------------------------------------------------------------------
extern "C" void kernel_launch(void* const* d_in, const int* in_sizes, int n_in,
                              void* d_out, int out_size, void* d_ws, size_t ws_size,
                              hipStream_t stream)
{
    (void)in_sizes; (void)n_in; (void)out_size; (void)ws_size;
    const float* z    = (const float*)d_in[0];
    float*       out  = (float*)d_out;
    u8*          q    = (u8*)d_ws;                                   // 2 MB fp4
    float*       spos = (float*)((char*)d_ws + (size_t)N * DB);      // 4096 f
    float*       star = spos + N;                                    // 528 f

    hipLaunchKernelGGL(norm_spos_kernel, dim3(N),    dim3(256), 0, stream, z, q, spos);
    hipLaunchKernelGGL(gram_kernel,      dim3(NTRI), dim3(512), 0, stream, q, star);
    hipLaunchKernelGGL(finalize_kernel,  dim3(1),    dim3(256), 0, stream, spos, star, out);
}